// Round 10
// baseline (128.981 us; speedup 1.0000x reference)
//
#include <hip/hip_runtime.h>

#define NAG 16
#define SPB 4        // scenes per block, one M=64 batch, single pass
#define NBLK 2048
#define R2f 64.0f

// Row stride must keep every row 16B-aligned (R6: misalignment is fatal).
// 136 u16 = 272 B = 17*16: aligned; moderate bank conflicts accepted (R4-proven).
#define X_STR 136    // xb/x1b row stride (u16)

typedef unsigned short u16;
typedef __attribute__((ext_vector_type(8))) short short8;
typedef __attribute__((ext_vector_type(4))) short short4v;
typedef __attribute__((ext_vector_type(4))) float f32x4;

#define MFMA(a, b, c)   __builtin_amdgcn_mfma_f32_16x16x32_bf16(a, b, c, 0, 0, 0)
#define MFMA16(a, b, c) __builtin_amdgcn_mfma_f32_16x16x16bf16_1k(a, b, c, 0, 0, 0)

// ws blob offsets in u16 units
#define OFF_B1 0        // [Wroot1;Wrel1]  K=128 N=128  S=4 T=8  (root s0..1, rel s2..3)
#define OFF_B2 16384    // [Wroot2;Wrel2]  K=256 N=128  S=8 T=8  (root s0..3, rel s4..7) [k-perm]
#define OFF_H1 49152    // Wh1             K=256 N=64   S=8 T=4                          [k-perm]
#define OFF_H2 65536    // Wh2 in MFMA16-A frag order: (nt*2+hh) x 64 lanes x 8 u16
#define OFF_H3 67584    // Wh3 in MFMA16-A frag order: 64 lanes x 8 u16 (h=0 lo, h=1 hi)
#define SWZ_UNITS 8512

__device__ __forceinline__ u16 f2b(float f) {            // RNE (swizzle only)
    unsigned u = __float_as_uint(f);
    unsigned r = u + 0x7FFFu + ((u >> 16) & 1u);
    return (u16)(r >> 16);
}
// fast round-to-nearest (ties up) — hot-kernel path; sub-ulp delta vs RNE
__device__ __forceinline__ unsigned rb(float f) {
    return (__float_as_uint(f) + 0x8000u) >> 16;
}
__device__ __forceinline__ unsigned pk2(float a, float b) {
    return ((__float_as_uint(a) + 0x8000u) >> 16) |
           ((__float_as_uint(b) + 0x8000u) & 0xFFFF0000u);
}

// ---------------- weight pre-swizzle: W[K][N] f32 -> fragment order bf16 -----
// B2/H1 use a k-permutation matching the pair-packed x1/x2 LDS layout:
// physical col p within each 32-group holds logical channel (p>>1) + 16*(p&1).
// H2/H3 are stored in MFMA16 A-fragment order (lane q,ln holds
// A[m=ln][k=h*16+q*4+j] = W[k][tile*16+ln]) for the transposed MLP tail.
__global__ __launch_bounds__(256) void swizzle_w(
    const float* __restrict__ Wrel1, const float* __restrict__ Wroot1,
    const float* __restrict__ Wrel2, const float* __restrict__ Wroot2,
    const float* __restrict__ Wh1,  const float* __restrict__ Wh2,
    const float* __restrict__ Wh3,  u16* __restrict__ ws)
{
    const int u = blockIdx.x * 256 + threadIdx.x;
    if (u >= SWZ_UNITS) return;

    if (u >= 8448) {                 // H3: 64 units, MFMA16-A frags (2 k-halves)
        const int v = u - 8448;
        const int lane = v & 63, qq = lane >> 4, ln2 = lane & 15;
        u16* dst = ws + OFF_H3 + v * 8;
        #pragma unroll
        for (int j = 0; j < 8; ++j) {
            const int k = (j >> 2) * 16 + qq * 4 + (j & 3);
            dst[j] = f2b(Wh3[k * 16 + ln2]);
        }
        return;
    }
    if (u >= 8192) {                 // H2: 256 units, MFMA16-A frags
        const int v = u - 8192;
        const int lane = v & 63, idx = v >> 6;     // idx = nt*2 + hh
        const int nt = idx >> 1, hh = idx & 1;
        const int qq = lane >> 4, ln2 = lane & 15;
        u16* dst = ws + OFF_H2 + v * 8;
        #pragma unroll
        for (int j = 0; j < 8; ++j) {
            const int h = 2 * hh + (j >> 2);
            const int k = h * 16 + qq * 4 + (j & 3);
            dst[j] = f2b(Wh2[k * 32 + nt * 16 + ln2]);
        }
        return;
    }

    int v, T, N, ksplit;
    bool perm = false;
    const float *W, *W2;
    u16* dst;
    if (u < 2048)      { v = u;        T = 8; N = 128; ksplit = 64;  W = Wroot1; W2 = Wrel1; dst = ws + OFF_B1 + v * 8; }
    else if (u < 6144) { v = u - 2048; T = 8; N = 128; ksplit = 128; W = Wroot2; W2 = Wrel2; dst = ws + OFF_B2 + v * 8; perm = true; }
    else               { v = u - 6144; T = 4; N = 64;  ksplit = 1 << 30; W = Wh1; W2 = Wh1; dst = ws + OFF_H1 + v * 8; perm = true; }
    const int lane = v & 63;
    const int t = (v >> 6) % T;
    const int s = (v >> 6) / T;
    const int n = t * 16 + (lane & 15);
    const int k0 = s * 32 + (lane >> 4) * 8;
    #pragma unroll
    for (int j = 0; j < 8; ++j) {
        const int k = k0 + j;
        const int kl = perm ? ((k & ~31) + ((k & 31) >> 1) + ((k & 1) << 4)) : k;
        const float val = (kl < ksplit) ? W[kl * N + n] : W2[(kl - ksplit) * N + n];
        dst[j] = f2b(val);
    }
}

__device__ __forceinline__ short8 ldfrag(const u16* __restrict__ ws, int off,
                                         int T, int s, int tile, int lane) {
    return *(const short8*)(ws + off + (size_t)(((s * T + tile) * 64 + lane) * 8));
}

// adjacency as A-fragment of a 16x16x16 MFMA: A[m=ln][k=q*4+j] = adj[ln][q*4+j]
// (adj is symmetric, diag excluded). 2 VGPRs of bf16 {0,1}.
__device__ __forceinline__ short4v make_adjA16(unsigned m, int q) {
    union { short4v v; unsigned u[2]; } r;
    const int k0 = q * 4;
    r.u[0] = (((m >> (k0 + 0)) & 1u) ? 0x3F80u     : 0u) |
             (((m >> (k0 + 1)) & 1u) ? 0x3F800000u : 0u);
    r.u[1] = (((m >> (k0 + 2)) & 1u) ? 0x3F80u     : 0u) |
             (((m >> (k0 + 3)) & 1u) ? 0x3F800000u : 0u);
    return r.v;
}

// pk2'd D-fragment (uint2) <-> B-operand of 16x16x16 MFMA. KEY IDENTITY
// (R4-proven bit-exact): D-frag of a 16x16 MFMA (lane q,ln holds rows q*4+r of
// col ln) IS the MFMA16 B-frag (k=q*4+r, n=ln). Also A/B register layouts
// coincide, so a "B-layout" weight frag passed as the A operand computes with
// the TRANSPOSED weight for free. The whole MLP tail exploits this.
union P2B { uint2 u; short4v s; };

// LDS (u16 units): xb  [64][136] (x cols0..63; later x2 cols0..127)   0..8704
//                  x1b [64][136] (x1)                                 8704..17408
// pool = 17408 u16 = 34.8 KB (+256B mask) -> 4 blocks/CU by LDS (vs R4's 3).
// Barriers: S0 | L1 | L2 = 3 (was 4): the MLP tail (GEMM3/4/5) is computed
// TRANSPOSED and wave-local: h1^T = Wh1^T@[x1|x2]^T (operand-swapped MFMA,
// reads only the wave's own 16 scene rows: 8 b128 vs 32), h2^T via MFMA16
// from pk2'd registers, out^T stored as one coalesced float4 per lane.
// No h1/h2 LDS buffers, no tail barrier, ~50 fewer LDS ops/wave.
// L1/L2/S0 byte-identical to R4 (best measured): serial wave-0 masks,
// register-path adjacency (MFMA16), pair-packing, fresh LDS A-reads.
__global__ __launch_bounds__(256) void gnn_fused5(
    const float* __restrict__ x, const float* __restrict__ pos,
    const float* __restrict__ brel1, const float* __restrict__ brel2,
    const float* __restrict__ bh1,  const float* __restrict__ bh2,
    const float* __restrict__ bh3,
    const u16* __restrict__ ws, float* __restrict__ out)
{
    __shared__ __align__(16) u16 pool[17408];
    __shared__ unsigned mask[64];
    u16* const xb  = pool;          // also x2
    u16* const x1b = pool + 8704;   // x1

    const int t = threadIdx.x;
    const int wv = t >> 6, lane = t & 63, ln = lane & 15, q = lane >> 4;
    const int c0 = 32 * wv;                 // wave's output-col base (L1/L2)
    const int n0 = 2 * wv, n1 = 2 * wv + 1;
    const size_t sA = (size_t)blockIdx.x * SPB;

    // ---- S0: stage x (f32->bf16) + adjacency masks ----
    {
        const int r = t >> 2, co = (t & 3) * 16;
        const float* src = x + (sA * 16 + r) * 64 + co;
        const float4 v0 = *(const float4*)(src);
        const float4 v1 = *(const float4*)(src + 4);
        const float4 v2 = *(const float4*)(src + 8);
        const float4 v3 = *(const float4*)(src + 12);
        uint4 ua, ub;
        ua.x = pk2(v0.x, v0.y); ua.y = pk2(v0.z, v0.w);
        ua.z = pk2(v1.x, v1.y); ua.w = pk2(v1.z, v1.w);
        ub.x = pk2(v2.x, v2.y); ub.y = pk2(v2.z, v2.w);
        ub.z = pk2(v3.x, v3.y); ub.w = pk2(v3.z, v3.w);
        *(uint4*)&xb[r * X_STR + co]     = ua;
        *(uint4*)&xb[r * X_STR + co + 8] = ub;
    }
    if (t < 64) {
        const int g = t >> 4, a = t & 15;
        const float* pp = pos + (sA + g) * (NAG * 2);
        const float ax = pp[2 * a], ay = pp[2 * a + 1];
        unsigned m = 0;
        for (int j = 0; j < NAG; ++j) {
            const float dx = ax - pp[2 * j], dy = ay - pp[2 * j + 1];
            if (dx * dx + dy * dy <= R2f && j != a) m |= (1u << j);
        }
        mask[g * 16 + a] = m;
    }
    __syncthreads();

    short4v adjA16[4];
    #pragma unroll
    for (int g = 0; g < 4; ++g) adjA16[g] = make_adjA16(mask[g * 16 + ln], q);

    // ---- L1: x1 = relu(adj@(x@Wrel1) + x@Wroot1 + b1) -> x1b (pair-packed) ----
    {
        short8 Brl[2][2], Bro[2][2], Af[4][2];
        uint2 P0[4], P1[4];
        #pragma unroll
        for (int s = 0; s < 2; ++s) {
            Brl[s][0] = ldfrag(ws, OFF_B1, 8, s + 2, n0, lane);
            Brl[s][1] = ldfrag(ws, OFF_B1, 8, s + 2, n1, lane);
        }
        #pragma unroll
        for (int m = 0; m < 4; ++m) {               // y1 kept in registers (P)
            Af[m][0] = *(const short8*)&xb[(m * 16 + ln) * X_STR + q * 8];
            Af[m][1] = *(const short8*)&xb[(m * 16 + ln) * X_STR + 32 + q * 8];
            f32x4 a0 = {0.f, 0.f, 0.f, 0.f}, a1 = a0;
            a0 = MFMA(Af[m][0], Brl[0][0], a0); a0 = MFMA(Af[m][1], Brl[1][0], a0);
            a1 = MFMA(Af[m][0], Brl[0][1], a1); a1 = MFMA(Af[m][1], Brl[1][1], a1);
            P0[m].x = pk2(a0[0], a0[1]); P0[m].y = pk2(a0[2], a0[3]);
            P1[m].x = pk2(a1[0], a1[1]); P1[m].y = pk2(a1[2], a1[3]);
        }
        #pragma unroll
        for (int s = 0; s < 2; ++s) {
            Bro[s][0] = ldfrag(ws, OFF_B1, 8, s, n0, lane);
            Bro[s][1] = ldfrag(ws, OFF_B1, 8, s, n1, lane);
        }
        const float b0 = brel1[c0 + ln], b1 = brel1[c0 + 16 + ln];
        #pragma unroll
        for (int g = 0; g < 4; ++g) {
            f32x4 a0 = {b0, b0, b0, b0}, a1 = {b1, b1, b1, b1};
            a0 = MFMA(Af[g][0], Bro[0][0], a0); a0 = MFMA(Af[g][1], Bro[1][0], a0);
            a1 = MFMA(Af[g][0], Bro[0][1], a1); a1 = MFMA(Af[g][1], Bro[1][1], a1);
            P2B p0; p0.u = P0[g];
            P2B p1; p1.u = P1[g];
            a0 = MFMA16(adjA16[g], p0.s, a0);
            a1 = MFMA16(adjA16[g], p1.s, a1);
            #pragma unroll
            for (int r2 = 0; r2 < 4; ++r2) {
                const int row = g * 16 + q * 4 + r2;
                *(unsigned*)&x1b[row * X_STR + c0 + 2 * ln] =
                    pk2(fmaxf(a0[r2], 0.f), fmaxf(a1[r2], 0.f));
            }
        }
    }
    __syncthreads();

    // ---- L2: x2 = relu(adj@(x1@Wrel2) + x1@Wroot2 + b2) -> xb (pair-packed) ----
    {
        short8 Brl[4][2];
        uint2 P0[4], P1[4];
        #pragma unroll
        for (int s = 0; s < 4; ++s) {
            Brl[s][0] = ldfrag(ws, OFF_B2, 8, s + 4, n0, lane);
            Brl[s][1] = ldfrag(ws, OFF_B2, 8, s + 4, n1, lane);
        }
        #pragma unroll
        for (int m = 0; m < 4; ++m) {               // y2 kept in registers (P)
            f32x4 a0 = {0.f, 0.f, 0.f, 0.f}, a1 = a0;
            #pragma unroll
            for (int s = 0; s < 4; ++s) {
                const short8 A = *(const short8*)&x1b[(m * 16 + ln) * X_STR + s * 32 + q * 8];
                a0 = MFMA(A, Brl[s][0], a0);
                a1 = MFMA(A, Brl[s][1], a1);
            }
            P0[m].x = pk2(a0[0], a0[1]); P0[m].y = pk2(a0[2], a0[3]);
            P1[m].x = pk2(a1[0], a1[1]); P1[m].y = pk2(a1[2], a1[3]);
        }
        short8 Bro[4][2];
        #pragma unroll
        for (int s = 0; s < 4; ++s) {
            Bro[s][0] = ldfrag(ws, OFF_B2, 8, s, n0, lane);
            Bro[s][1] = ldfrag(ws, OFF_B2, 8, s, n1, lane);
        }
        const float b0 = brel2[c0 + ln], b1 = brel2[c0 + 16 + ln];
        #pragma unroll
        for (int g = 0; g < 4; ++g) {
            f32x4 a0 = {b0, b0, b0, b0}, a1 = {b1, b1, b1, b1};
            #pragma unroll
            for (int s = 0; s < 4; ++s) {
                const short8 A = *(const short8*)&x1b[(g * 16 + ln) * X_STR + s * 32 + q * 8];
                a0 = MFMA(A, Bro[s][0], a0);
                a1 = MFMA(A, Bro[s][1], a1);
            }
            P2B p0; p0.u = P0[g];
            P2B p1; p1.u = P1[g];
            a0 = MFMA16(adjA16[g], p0.s, a0);
            a1 = MFMA16(adjA16[g], p1.s, a1);
            #pragma unroll
            for (int r2 = 0; r2 < 4; ++r2) {
                const int row = g * 16 + q * 4 + r2;
                *(unsigned*)&xb[row * X_STR + c0 + 2 * ln] =
                    pk2(fmaxf(a0[r2], 0.f), fmaxf(a1[r2], 0.f));
            }
        }
    }
    __syncthreads();

    // ---- GEMM3+4+5 fused, TRANSPOSED, wave-local (scene wv) — no barriers ----
    {
        // x-frags for this wave's scene rows only (read once; B-operands)
        short8 X1[4], X2[4];
        #pragma unroll
        for (int s = 0; s < 4; ++s) {
            X1[s] = *(const short8*)&x1b[(wv * 16 + ln) * X_STR + s * 32 + q * 8];
            X2[s] = *(const short8*)&xb [(wv * 16 + ln) * X_STR + s * 32 + q * 8];
        }
        // h1^T = Wh1^T @ [x1|x2]^T  (Wh1 frag as A-operand == transpose)
        P2B H1f[4];
        #pragma unroll
        for (int mt = 0; mt < 4; ++mt) {
            const float4 bv = *(const float4*)(bh1 + mt * 16 + q * 4);
            f32x4 a = {bv.x, bv.y, bv.z, bv.w};
            #pragma unroll
            for (int s = 0; s < 4; ++s)
                a = MFMA(ldfrag(ws, OFF_H1, 4, s, mt, lane), X1[s], a);
            #pragma unroll
            for (int s = 0; s < 4; ++s)
                a = MFMA(ldfrag(ws, OFF_H1, 4, s + 4, mt, lane), X2[s], a);
            H1f[mt].u.x = pk2(fmaxf(a[0], 0.f), fmaxf(a[1], 0.f));
            H1f[mt].u.y = pk2(fmaxf(a[2], 0.f), fmaxf(a[3], 0.f));
        }
        // h2^T = Wh2^T @ h1^T  (k=64 via 4 MFMA16 from registers)
        P2B H2f[2];
        #pragma unroll
        for (int nt = 0; nt < 2; ++nt) {
            const float4 bv = *(const float4*)(bh2 + nt * 16 + q * 4);
            f32x4 a = {bv.x, bv.y, bv.z, bv.w};
            #pragma unroll
            for (int hh = 0; hh < 2; ++hh) {
                union { short8 v; short4v h[2]; } W;
                W.v = *(const short8*)(ws + OFF_H2 +
                        (size_t)(((nt * 2 + hh) * 64 + lane) * 8));
                a = MFMA16(W.h[0], H1f[2 * hh].s, a);
                a = MFMA16(W.h[1], H1f[2 * hh + 1].s, a);
            }
            H2f[nt].u.x = pk2(fmaxf(a[0], 0.f), fmaxf(a[1], 0.f));
            H2f[nt].u.y = pk2(fmaxf(a[2], 0.f), fmaxf(a[3], 0.f));
        }
        // out^T = Wh3^T @ h2^T  (k=32 via 2 MFMA16); store float4 per lane
        {
            const float4 bv = *(const float4*)(bh3 + q * 4);
            f32x4 a = {bv.x, bv.y, bv.z, bv.w};
            union { short8 v; short4v h[2]; } W;
            W.v = *(const short8*)(ws + OFF_H3 + (size_t)(lane * 8));
            a = MFMA16(W.h[0], H2f[0].s, a);
            a = MFMA16(W.h[1], H2f[1].s, a);
            *(float4*)&out[(sA * 16 + wv * 16 + ln) * 16 + q * 4] = *(float4*)&a;
        }
    }
}

extern "C" void kernel_launch(void* const* d_in, const int* in_sizes, int n_in,
                              void* d_out, int out_size, void* d_ws, size_t ws_size,
                              hipStream_t stream) {
    const float* x      = (const float*)d_in[0];
    const float* pos    = (const float*)d_in[1];
    const float* Wrel1  = (const float*)d_in[2];
    const float* brel1  = (const float*)d_in[3];
    const float* Wroot1 = (const float*)d_in[4];
    const float* Wrel2  = (const float*)d_in[5];
    const float* brel2  = (const float*)d_in[6];
    const float* Wroot2 = (const float*)d_in[7];
    const float* Wh1    = (const float*)d_in[8];
    const float* bh1    = (const float*)d_in[9];
    const float* Wh2    = (const float*)d_in[10];
    const float* bh2    = (const float*)d_in[11];
    const float* Wh3    = (const float*)d_in[12];
    const float* bh3    = (const float*)d_in[13];
    u16* ws = (u16*)d_ws;

    swizzle_w<<<(SWZ_UNITS + 255) / 256, 256, 0, stream>>>(
        Wrel1, Wroot1, Wrel2, Wroot2, Wh1, Wh2, Wh3, ws);
    gnn_fused5<<<NBLK, 256, 0, stream>>>(
        x, pos, brel1, brel2, bh1, bh2, bh3, ws, (float*)d_out);
}

// Round 11
// 121.127 us; speedup vs baseline: 1.0648x; 1.0648x over previous
//
#include <hip/hip_runtime.h>

#define NAG 16
#define SPB 4        // scenes per block, one M=64 batch, single pass
#define NBLK 2048
#define R2f 64.0f

typedef unsigned short u16;
typedef __attribute__((ext_vector_type(8))) short short8;
typedef __attribute__((ext_vector_type(4))) short short4v;
typedef __attribute__((ext_vector_type(4))) float f32x4;

#define MFMA(a, b, c)   __builtin_amdgcn_mfma_f32_16x16x32_bf16(a, b, c, 0, 0, 0)
#define MFMA16(a, b, c) __builtin_amdgcn_mfma_f32_16x16x16bf16_1k(a, b, c, 0, 0, 0)

// ws blob offsets in u16 units
#define OFF_B1 0        // [Wroot1;Wrel1]  K=128 N=128  S=4 T=8  (root s0..1, rel s2..3)
#define OFF_B2 16384    // [Wroot2;Wrel2]  K=256 N=128  S=8 T=8  (root s0..3, rel s4..7) [k-perm]
#define OFF_H1 49152    // Wh1             K=256 N=64   S=8 T=4                          [k-perm]
#define OFF_H2 65536    // Wh2             K=64  N=32   S=2 T=2
#define OFF_H3 67584    // Wh3             K=32  N=16   S=1 T=1
#define SWZ_UNITS 8512

__device__ __forceinline__ u16 f2b(float f) {            // RNE (swizzle only)
    unsigned u = __float_as_uint(f);
    unsigned r = u + 0x7FFFu + ((u >> 16) & 1u);
    return (u16)(r >> 16);
}
// fast round-to-nearest (ties up) — hot-kernel path; sub-ulp delta vs RNE
__device__ __forceinline__ unsigned rb(float f) {
    return (__float_as_uint(f) + 0x8000u) >> 16;
}
__device__ __forceinline__ unsigned pk2(float a, float b) {
    return ((__float_as_uint(a) + 0x8000u) >> 16) |
           ((__float_as_uint(b) + 0x8000u) & 0xFFFF0000u);
}

// ---------------- weight pre-swizzle: W[K][N] f32 -> fragment order bf16 -----
// B2/H1 use a k-permutation matching the pair-packed x1/x2 LDS layout:
// physical col p within each 32-group holds logical channel (p>>1) + 16*(p&1).
__global__ __launch_bounds__(256) void swizzle_w(
    const float* __restrict__ Wrel1, const float* __restrict__ Wroot1,
    const float* __restrict__ Wrel2, const float* __restrict__ Wroot2,
    const float* __restrict__ Wh1,  const float* __restrict__ Wh2,
    const float* __restrict__ Wh3,  u16* __restrict__ ws)
{
    const int u = blockIdx.x * 256 + threadIdx.x;
    if (u >= SWZ_UNITS) return;
    int v, T, N, ksplit;
    bool perm = false;
    const float *W, *W2;
    u16* dst;
    if (u < 2048)      { v = u;        T = 8; N = 128; ksplit = 64;  W = Wroot1; W2 = Wrel1; dst = ws + OFF_B1 + v * 8; }
    else if (u < 6144) { v = u - 2048; T = 8; N = 128; ksplit = 128; W = Wroot2; W2 = Wrel2; dst = ws + OFF_B2 + v * 8; perm = true; }
    else if (u < 8192) { v = u - 6144; T = 4; N = 64;  ksplit = 1 << 30; W = Wh1; W2 = Wh1; dst = ws + OFF_H1 + v * 8; perm = true; }
    else if (u < 8448) { v = u - 8192; T = 2; N = 32;  ksplit = 1 << 30; W = Wh2; W2 = Wh2; dst = ws + OFF_H2 + v * 8; }
    else               { v = u - 8448; T = 1; N = 16;  ksplit = 1 << 30; W = Wh3; W2 = Wh3; dst = ws + OFF_H3 + v * 8; }
    const int lane = v & 63;
    const int t = (v >> 6) % T;
    const int s = (v >> 6) / T;
    const int n = t * 16 + (lane & 15);
    const int k0 = s * 32 + (lane >> 4) * 8;
    #pragma unroll
    for (int j = 0; j < 8; ++j) {
        const int k = k0 + j;
        const int kl = perm ? ((k & ~31) + ((k & 31) >> 1) + ((k & 1) << 4)) : k;
        const float val = (kl < ksplit) ? W[kl * N + n] : W2[(kl - ksplit) * N + n];
        dst[j] = f2b(val);
    }
}

__device__ __forceinline__ short8 ldfrag(const u16* __restrict__ ws, int off,
                                         int T, int s, int tile, int lane) {
    return *(const short8*)(ws + off + (size_t)(((s * T + tile) * 64 + lane) * 8));
}

// adjacency as A-fragment of a 16x16x16 MFMA: A[m=ln][k=q*4+j] = adj[ln][q*4+j]
// (adj is symmetric, diag excluded). 2 VGPRs of bf16 {0,1}.
__device__ __forceinline__ short4v make_adjA16(unsigned m, int q) {
    union { short4v v; unsigned u[2]; } r;
    const int k0 = q * 4;
    r.u[0] = (((m >> (k0 + 0)) & 1u) ? 0x3F80u     : 0u) |
             (((m >> (k0 + 1)) & 1u) ? 0x3F800000u : 0u);
    r.u[1] = (((m >> (k0 + 2)) & 1u) ? 0x3F80u     : 0u) |
             (((m >> (k0 + 3)) & 1u) ? 0x3F800000u : 0u);
    return r.v;
}

// pk2'd D-fragment (uint2) -> B-operand of 16x16x16 MFMA.
// KEY IDENTITY (R4-proven bit-exact): the D-frag of a 16x16 MFMA (lane q,ln
// holds rows q*4+{0..3} of col ln) IS the B-frag layout of a 16x16x16 MFMA
// (k=q*4+{0..3}, n=ln). So agg = adj @ y consumes the y accumulators DIRECTLY
// from registers: no LDS transpose round-trip per GraphConv layer.
union P2B { uint2 u; short4v s; };

// LDS (u16 units): xb  [64][136] (x cols0..63; later x2 cols0..127)   0..8704
//                  h1r [64][72]  (h1 after GEMM3)                     8704..13312
//                  x1b [64][136] (x1; later h2 [64][40])              13312..22016
// 44.3 KB -> 3 blocks/CU. Barriers: S0|L1|L2|GEMM3|GEMM45 = 4.
// FINAL STATE = R4, the session's best-measured configuration (121.7 us).
// Session evidence for why each alternative lost:
//  - stride 132/68 (conflict-free): rows lose 16B alignment -> b128 splits (R6, -42us)
//  - XOR block swizzle: address-math tax, 4th block never materialized (R9)
//  - long-lived register tiles (Af2): compiler scheduling collapse (R5)
//  - transposed MLP tail: 4x Wh1 fetch on the critical chain (R10)
//  - occupancy pushes (SPB=2, LB(256,4)): per-block fixed costs dominate (R1)
// Two fixed 43us poison-fills bound the harness measurement from below.
__global__ __launch_bounds__(256) void gnn_fused5(
    const float* __restrict__ x, const float* __restrict__ pos,
    const float* __restrict__ brel1, const float* __restrict__ brel2,
    const float* __restrict__ bh1,  const float* __restrict__ bh2,
    const float* __restrict__ bh3,
    const u16* __restrict__ ws, float* __restrict__ out)
{
    __shared__ __align__(16) u16 pool[22016];
    __shared__ unsigned mask[64];
    u16* const xb  = pool;          // also x2
    u16* const h1r = pool + 8704;   // h1
    u16* const x1b = pool + 13312;  // also h2

    const int t = threadIdx.x;
    const int wv = t >> 6, lane = t & 63, ln = lane & 15, q = lane >> 4;
    const int c0 = 32 * wv;                 // wave's output-col base (L1/L2)
    const int n0 = 2 * wv, n1 = 2 * wv + 1;
    const size_t sA = (size_t)blockIdx.x * SPB;

    // ---- S0: stage x (f32->bf16) + adjacency masks ----
    {
        const int r = t >> 2, co = (t & 3) * 16;
        const float* src = x + (sA * 16 + r) * 64 + co;
        const float4 v0 = *(const float4*)(src);
        const float4 v1 = *(const float4*)(src + 4);
        const float4 v2 = *(const float4*)(src + 8);
        const float4 v3 = *(const float4*)(src + 12);
        uint4 ua, ub;
        ua.x = pk2(v0.x, v0.y); ua.y = pk2(v0.z, v0.w);
        ua.z = pk2(v1.x, v1.y); ua.w = pk2(v1.z, v1.w);
        ub.x = pk2(v2.x, v2.y); ub.y = pk2(v2.z, v2.w);
        ub.z = pk2(v3.x, v3.y); ub.w = pk2(v3.z, v3.w);
        *(uint4*)&xb[r * 136 + co]     = ua;
        *(uint4*)&xb[r * 136 + co + 8] = ub;
    }
    if (t < 64) {
        const int g = t >> 4, a = t & 15;
        const float* pp = pos + (sA + g) * (NAG * 2);
        const float ax = pp[2 * a], ay = pp[2 * a + 1];
        unsigned m = 0;
        for (int j = 0; j < NAG; ++j) {
            const float dx = ax - pp[2 * j], dy = ay - pp[2 * j + 1];
            if (dx * dx + dy * dy <= R2f && j != a) m |= (1u << j);
        }
        mask[g * 16 + a] = m;
    }
    __syncthreads();

    short4v adjA16[4];
    #pragma unroll
    for (int g = 0; g < 4; ++g) adjA16[g] = make_adjA16(mask[g * 16 + ln], q);

    // ---- L1: x1 = relu(adj@(x@Wrel1) + x@Wroot1 + b1) -> x1b (pair-packed) ----
    {
        short8 Brl[2][2], Bro[2][2], Af[4][2];
        uint2 P0[4], P1[4];
        #pragma unroll
        for (int s = 0; s < 2; ++s) {
            Brl[s][0] = ldfrag(ws, OFF_B1, 8, s + 2, n0, lane);
            Brl[s][1] = ldfrag(ws, OFF_B1, 8, s + 2, n1, lane);
        }
        #pragma unroll
        for (int m = 0; m < 4; ++m) {               // y1 kept in registers (P)
            Af[m][0] = *(const short8*)&xb[(m * 16 + ln) * 136 + q * 8];
            Af[m][1] = *(const short8*)&xb[(m * 16 + ln) * 136 + 32 + q * 8];
            f32x4 a0 = {0.f, 0.f, 0.f, 0.f}, a1 = a0;
            a0 = MFMA(Af[m][0], Brl[0][0], a0); a0 = MFMA(Af[m][1], Brl[1][0], a0);
            a1 = MFMA(Af[m][0], Brl[0][1], a1); a1 = MFMA(Af[m][1], Brl[1][1], a1);
            P0[m].x = pk2(a0[0], a0[1]); P0[m].y = pk2(a0[2], a0[3]);
            P1[m].x = pk2(a1[0], a1[1]); P1[m].y = pk2(a1[2], a1[3]);
        }
        #pragma unroll
        for (int s = 0; s < 2; ++s) {
            Bro[s][0] = ldfrag(ws, OFF_B1, 8, s, n0, lane);
            Bro[s][1] = ldfrag(ws, OFF_B1, 8, s, n1, lane);
        }
        const float b0 = brel1[c0 + ln], b1 = brel1[c0 + 16 + ln];
        #pragma unroll
        for (int g = 0; g < 4; ++g) {
            f32x4 a0 = {b0, b0, b0, b0}, a1 = {b1, b1, b1, b1};
            a0 = MFMA(Af[g][0], Bro[0][0], a0); a0 = MFMA(Af[g][1], Bro[1][0], a0);
            a1 = MFMA(Af[g][0], Bro[0][1], a1); a1 = MFMA(Af[g][1], Bro[1][1], a1);
            P2B p0; p0.u = P0[g];
            P2B p1; p1.u = P1[g];
            a0 = MFMA16(adjA16[g], p0.s, a0);
            a1 = MFMA16(adjA16[g], p1.s, a1);
            #pragma unroll
            for (int r2 = 0; r2 < 4; ++r2) {
                const int row = g * 16 + q * 4 + r2;
                *(unsigned*)&x1b[row * 136 + c0 + 2 * ln] =
                    pk2(fmaxf(a0[r2], 0.f), fmaxf(a1[r2], 0.f));
            }
        }
    }
    __syncthreads();

    // ---- L2: x2 = relu(adj@(x1@Wrel2) + x1@Wroot2 + b2) -> xb (pair-packed) ----
    {
        short8 Brl[4][2];
        uint2 P0[4], P1[4];
        #pragma unroll
        for (int s = 0; s < 4; ++s) {
            Brl[s][0] = ldfrag(ws, OFF_B2, 8, s + 4, n0, lane);
            Brl[s][1] = ldfrag(ws, OFF_B2, 8, s + 4, n1, lane);
        }
        #pragma unroll
        for (int m = 0; m < 4; ++m) {               // y2 kept in registers (P)
            f32x4 a0 = {0.f, 0.f, 0.f, 0.f}, a1 = a0;
            #pragma unroll
            for (int s = 0; s < 4; ++s) {
                const short8 A = *(const short8*)&x1b[(m * 16 + ln) * 136 + s * 32 + q * 8];
                a0 = MFMA(A, Brl[s][0], a0);
                a1 = MFMA(A, Brl[s][1], a1);
            }
            P0[m].x = pk2(a0[0], a0[1]); P0[m].y = pk2(a0[2], a0[3]);
            P1[m].x = pk2(a1[0], a1[1]); P1[m].y = pk2(a1[2], a1[3]);
        }
        short8 Bro[4][2];
        #pragma unroll
        for (int s = 0; s < 4; ++s) {
            Bro[s][0] = ldfrag(ws, OFF_B2, 8, s, n0, lane);
            Bro[s][1] = ldfrag(ws, OFF_B2, 8, s, n1, lane);
        }
        const float b0 = brel2[c0 + ln], b1 = brel2[c0 + 16 + ln];
        #pragma unroll
        for (int g = 0; g < 4; ++g) {
            f32x4 a0 = {b0, b0, b0, b0}, a1 = {b1, b1, b1, b1};
            #pragma unroll
            for (int s = 0; s < 4; ++s) {
                const short8 A = *(const short8*)&x1b[(g * 16 + ln) * 136 + s * 32 + q * 8];
                a0 = MFMA(A, Bro[s][0], a0);
                a1 = MFMA(A, Bro[s][1], a1);
            }
            P2B p0; p0.u = P0[g];
            P2B p1; p1.u = P1[g];
            a0 = MFMA16(adjA16[g], p0.s, a0);
            a1 = MFMA16(adjA16[g], p1.s, a1);
            #pragma unroll
            for (int r2 = 0; r2 < 4; ++r2) {
                const int row = g * 16 + q * 4 + r2;
                *(unsigned*)&xb[row * 136 + c0 + 2 * ln] =
                    pk2(fmaxf(a0[r2], 0.f), fmaxf(a1[r2], 0.f));
            }
        }
    }
    __syncthreads();

    // ---- GEMM3: h1 = relu([x1|x2] @ Wh1 + bh1), n-tile = wv -> h1r ----
    {
        short8 Bf[8];
        #pragma unroll
        for (int s = 0; s < 8; ++s) Bf[s] = ldfrag(ws, OFF_H1, 4, s, wv, lane);
        const float b = bh1[wv * 16 + ln];
        #pragma unroll
        for (int m = 0; m < 4; ++m) {
            f32x4 a = {b, b, b, b}, c = {0.f, 0.f, 0.f, 0.f};
            #pragma unroll
            for (int s = 0; s < 4; ++s) {
                const short8 A1 = *(const short8*)&x1b[(m * 16 + ln) * 136 + s * 32 + q * 8];
                const short8 A2 = *(const short8*)&xb[(m * 16 + ln) * 136 + s * 32 + q * 8];
                a = MFMA(A1, Bf[s], a);
                c = MFMA(A2, Bf[s + 4], c);
            }
            #pragma unroll
            for (int r2 = 0; r2 < 4; ++r2)
                h1r[(m * 16 + q * 4 + r2) * 72 + wv * 16 + ln] = (u16)rb(fmaxf(a[r2] + c[r2], 0.f));
        }
    }
    __syncthreads();

    // ---- GEMM4+5 (wave-local: wave wv = scene wv): h2 then out ----
    {
        u16* h2b = x1b;                              // x1 dead
        const short8 A0 = *(const short8*)&h1r[(wv * 16 + ln) * 72 + q * 8];
        const short8 A1 = *(const short8*)&h1r[(wv * 16 + ln) * 72 + 32 + q * 8];
        #pragma unroll
        for (int nt = 0; nt < 2; ++nt) {
            const short8 B0 = ldfrag(ws, OFF_H2, 2, 0, nt, lane);
            const short8 B1 = ldfrag(ws, OFF_H2, 2, 1, nt, lane);
            const float b = bh2[nt * 16 + ln];
            f32x4 a = {b, b, b, b};
            a = MFMA(A0, B0, a);
            a = MFMA(A1, B1, a);
            #pragma unroll
            for (int r2 = 0; r2 < 4; ++r2)
                h2b[(wv * 16 + q * 4 + r2) * 40 + nt * 16 + ln] = (u16)rb(fmaxf(a[r2], 0.f));
        }
        const short8 A = *(const short8*)&h2b[(wv * 16 + ln) * 40 + q * 8];
        const short8 B = ldfrag(ws, OFF_H3, 1, 0, 0, lane);
        const float b = bh3[ln];
        f32x4 a = {b, b, b, b};
        a = MFMA(A, B, a);
        #pragma unroll
        for (int r2 = 0; r2 < 4; ++r2)
            out[(sA * 16 + wv * 16 + q * 4 + r2) * 16 + ln] = a[r2];
    }
}

extern "C" void kernel_launch(void* const* d_in, const int* in_sizes, int n_in,
                              void* d_out, int out_size, void* d_ws, size_t ws_size,
                              hipStream_t stream) {
    const float* x      = (const float*)d_in[0];
    const float* pos    = (const float*)d_in[1];
    const float* Wrel1  = (const float*)d_in[2];
    const float* brel1  = (const float*)d_in[3];
    const float* Wroot1 = (const float*)d_in[4];
    const float* Wrel2  = (const float*)d_in[5];
    const float* brel2  = (const float*)d_in[6];
    const float* Wroot2 = (const float*)d_in[7];
    const float* Wh1    = (const float*)d_in[8];
    const float* bh1    = (const float*)d_in[9];
    const float* Wh2    = (const float*)d_in[10];
    const float* bh2    = (const float*)d_in[11];
    const float* Wh3    = (const float*)d_in[12];
    const float* bh3    = (const float*)d_in[13];
    u16* ws = (u16*)d_ws;

    swizzle_w<<<(SWZ_UNITS + 255) / 256, 256, 0, stream>>>(
        Wrel1, Wroot1, Wrel2, Wroot2, Wh1, Wh2, Wh3, ws);
    gnn_fused5<<<NBLK, 256, 0, stream>>>(
        x, pos, brel1, brel2, bh1, bh2, bh3, ws, (float*)d_out);
}